// Round 1
// baseline (49.210 us; speedup 1.0000x reference)
//
#include <hip/hip_runtime.h>

#define WEIGHT_POSITIVE 0.1f

// Pass 1: grid-stride vectorized partial reduction. One float partial per block.
__global__ __launch_bounds__(256) void wmse_partial(
    const float* __restrict__ pred,
    const int* __restrict__ tgt,
    float* __restrict__ partial,
    int n_vec,   // number of float4/int4 groups
    int n)       // total elements (for scalar tail)
{
    const int tid    = blockIdx.x * blockDim.x + threadIdx.x;
    const int stride = gridDim.x * blockDim.x;

    const float4* __restrict__ p4 = reinterpret_cast<const float4*>(pred);
    const int4*   __restrict__ t4 = reinterpret_cast<const int4*>(tgt);

    float acc = 0.0f;

    for (int i = tid; i < n_vec; i += stride) {
        float4 p = p4[i];
        int4   t = t4[i];

        {
            float tf = (float)t.x;
            float d  = p.x - tf;
            bool mis = (p.x >= 0.5f) != (t.x == 1);
            acc += (mis ? (1.0f + WEIGHT_POSITIVE) : 1.0f) * d * d;
        }
        {
            float tf = (float)t.y;
            float d  = p.y - tf;
            bool mis = (p.y >= 0.5f) != (t.y == 1);
            acc += (mis ? (1.0f + WEIGHT_POSITIVE) : 1.0f) * d * d;
        }
        {
            float tf = (float)t.z;
            float d  = p.z - tf;
            bool mis = (p.z >= 0.5f) != (t.z == 1);
            acc += (mis ? (1.0f + WEIGHT_POSITIVE) : 1.0f) * d * d;
        }
        {
            float tf = (float)t.w;
            float d  = p.w - tf;
            bool mis = (p.w >= 0.5f) != (t.w == 1);
            acc += (mis ? (1.0f + WEIGHT_POSITIVE) : 1.0f) * d * d;
        }
    }

    // scalar tail (n not divisible by 4) — grid-stride over the remainder
    for (int i = n_vec * 4 + tid; i < n; i += stride) {
        float p  = pred[i];
        int   t  = tgt[i];
        float tf = (float)t;
        float d  = p - tf;
        bool mis = (p >= 0.5f) != (t == 1);
        acc += (mis ? (1.0f + WEIGHT_POSITIVE) : 1.0f) * d * d;
    }

    // wave-64 reduction
    #pragma unroll
    for (int off = 32; off > 0; off >>= 1)
        acc += __shfl_down(acc, off, 64);

    __shared__ float s[4];  // 256 threads = 4 waves
    const int lane = threadIdx.x & 63;
    const int wave = threadIdx.x >> 6;
    if (lane == 0) s[wave] = acc;
    __syncthreads();

    if (threadIdx.x == 0)
        partial[blockIdx.x] = s[0] + s[1] + s[2] + s[3];
}

// Pass 2: single block reduces all partials, writes the mean.
__global__ __launch_bounds__(256) void wmse_final(
    const float* __restrict__ partial,
    int nb,
    float* __restrict__ out,
    float inv_n)
{
    float acc = 0.0f;
    for (int i = threadIdx.x; i < nb; i += blockDim.x)
        acc += partial[i];

    #pragma unroll
    for (int off = 32; off > 0; off >>= 1)
        acc += __shfl_down(acc, off, 64);

    __shared__ float s[4];
    const int lane = threadIdx.x & 63;
    const int wave = threadIdx.x >> 6;
    if (lane == 0) s[wave] = acc;
    __syncthreads();

    if (threadIdx.x == 0)
        out[0] = (s[0] + s[1] + s[2] + s[3]) * inv_n;
}

extern "C" void kernel_launch(void* const* d_in, const int* in_sizes, int n_in,
                              void* d_out, int out_size, void* d_ws, size_t ws_size,
                              hipStream_t stream) {
    const float* pred = (const float*)d_in[0];
    const int*   tgt  = (const int*)d_in[1];
    float*       out  = (float*)d_out;
    float*       ws   = (float*)d_ws;

    const int n     = in_sizes[0];
    const int n_vec = n / 4;

    // memory-bound: cap at ~8 blocks/CU and grid-stride the rest (G11)
    int blocks = (n_vec + 255) / 256;
    if (blocks > 2048) blocks = 2048;
    if (blocks < 1) blocks = 1;

    wmse_partial<<<blocks, 256, 0, stream>>>(pred, tgt, ws, n_vec, n);
    wmse_final<<<1, 256, 0, stream>>>(ws, blocks, out, 1.0f / (float)n);
}